// Round 17
// baseline (293.030 us; speedup 1.0000x reference)
//
#include <hip/hip_runtime.h>
#include <math.h>

#define NANG 120
#define NANGH 60
#define NB   16
#define H    50
#define SD   100
#define NBIN 51        // rfft bins of length-100
#define PADB 7         // top pad rows of B-hat (rows -7..-1 zero)
#define BROWS 69       // stored rows: r in [-7, 61]
#define BST  102       // B-hat row stride
#define WST  104       // g_W row stride
#define RTST 52        // Rt row stride
#define CLAG 100       // C lag dim
#define AX   58        // g_Arec x rows (50 real + 8 zero pad)

// ---- device-global scratch ----
__device__ __align__(16) float g_Arec[NB*2*AX*NBIN*2 + 64]; // [b][c][x][om][2], x 50..57 zero
__device__ __align__(16) float g_ligc[NB*2*H*H];            // [b][c][y][x]
__device__ __align__(16) float g_W[H*WST];                  // [y][2*om+p] = (cos, -sin)
__device__ __align__(16) float g_P[NBIN*128 + 64];          // [om][2*dy+p] = (cos,sin), dy 0..50
__device__ __align__(16) float g_C[(size_t)NANGH*NB*15300]; // [pair]{Ci1, Wr, Wi}[51][100]
__device__ unsigned long long g_key[NB];

// per-wave tile schedule (4 slots): corr d0 in [-49,47]; conv encoded e0+200; 999 = none.
__device__ const int g_sched2[8][4] = {
  {-1,-17,-49,999},{248,232,200,999},{-9,15,296,999},{240,264,47,999},
  {7,-25,208,999},{256,224,-41,999},{23,-33,216,39},{272,280,31,288}
};

// ================= prep: conv+relu+combine, rec spectrum, tables =================
// grid = NB*8 + 1. blocks (b,part): part = blk&7 handles ~6-7 oms
__global__ __launch_bounds__(512) void k_prep(const float* __restrict__ rec,
                                              const float* __restrict__ lig,
                                              const float* __restrict__ wr,
                                              const float* __restrict__ br,
                                              const float* __restrict__ wsc) {
  const int blk = blockIdx.x;
  const int tid = threadIdx.x;
  if (blk == NB*8) {
    for (int u = tid; u < H*WST; u += 512) {
      int y = u / WST, col = u % WST;
      float v = 0.f;
      if (col < 2*NBIN) {
        int om = col >> 1;
        int k = (om * y) % SD;
        double ang = 6.283185307179586 * (double)k / 100.0;
        v = (col & 1) ? (float)(-sin(ang)) : (float)cos(ang);
      }
      g_W[u] = v;
    }
    for (int u = tid; u < NBIN*128; u += 512) {
      int om = u >> 7, q = u & 127;
      int dy = q >> 1;
      float v = 0.f;
      if (dy <= 50) {
        int k = (om * dy) % SD;
        double ang = 6.283185307179586 * (double)k / 100.0;
        v = (q & 1) ? (float)sin(ang) : (float)cos(ang);
      }
      g_P[u] = v;
    }
    for (int i = tid; i < NB; i += 512) g_key[i] = (0x80000000ULL << 21);
    return;
  }
  const int b = blk >> 3;
  const int part = blk & 7;
  const int omBase = (part < 3) ? part*7 : 21 + (part-3)*6;
  const int nOm = (part < 3) ? 7 : 6;
  __shared__ float recf[2*H*H];
  __shared__ float tbl[SD*2];
  for (int k = tid; k < SD; k += 512) {
    double ang = 6.283185307179586 * (double)k / 100.0;
    tbl[2*k]   = (float)cos(ang);
    tbl[2*k+1] = (float)sin(ang);
  }
  const float* rimg = rec + b*H*H;
  const float* limg = lig + b*H*H;
  for (int p = tid; p < H*H; p += 512) {
    int i = p / H, j = p - (p/H)*H;
    float ar0 = br[0], ar1 = br[1], al0 = br[0], al1 = br[1];
    for (int di = 0; di < 3; ++di) {
      int ii = i + di - 1;
      if (ii < 0 || ii >= H) continue;
      for (int dj = 0; dj < 3; ++dj) {
        int jj = j + dj - 1;
        if (jj < 0 || jj >= H) continue;
        float rv = rimg[ii*H+jj], lv = limg[ii*H+jj];
        float w0 = wr[di*3 + dj], w1 = wr[9 + di*3 + dj];
        ar0 += w0*rv; ar1 += w1*rv; al0 += w0*lv; al1 += w1*lv;
      }
    }
    ar0 = fmaxf(ar0, 0.f); ar1 = fmaxf(ar1, 0.f);
    recf[p] = ar0; recf[H*H + p] = ar1;
    if (part == 0) {
      al0 = fmaxf(al0, 0.f); al1 = fmaxf(al1, 0.f);
      g_ligc[((b*2+0)*H + i)*H + j] = wsc[0]*al0 + wsc[1]*al1;
      g_ligc[((b*2+1)*H + i)*H + j] = wsc[2]*al0 + wsc[3]*al1;
    }
  }
  if (part == 0) {
    for (int u = tid; u < 2*8*102; u += 512) {
      int c = u / 816; int r = u % 816;
      int x = 50 + r / 102; int q = r % 102;
      g_Arec[((b*2+c)*AX + x)*102 + q] = 0.f;
    }
  }
  __syncthreads();
  for (int u = tid; u < 2*H*nOm; u += 512) {
    int om = omBase + u % nOm;
    int rest = u / nOm; int x = rest % H; int c = rest / H;
    const float* row = recf + (c*H + x)*H;
    float sr = 0.f, si = 0.f;
    int k = 0;
    for (int y = 0; y < H; ++y) {
      float rv = row[y];
      sr += rv * tbl[2*k];
      si -= rv * tbl[2*k+1];
      k += om; if (k >= SD) k -= SD;
    }
    float* dst = g_Arec + ((b*2+c)*AX + x)*102 + 2*om;
    dst[0] = sr; dst[1] = si;
  }
}

// corr step: C(d) = sum conj(A)*B
#define STEP8(uu) do { \
  float Ar = ar_[(uu)&7], Ai = ai_[(uu)&7]; \
  { const int sl=(uu)&7;     cr0 += Ar*br_[sl]+Ai*bi_[sl]; ci0 += Ar*bi_[sl]-Ai*br_[sl]; } \
  { const int sl=((uu)+1)&7; cr1 += Ar*br_[sl]+Ai*bi_[sl]; ci1 += Ar*bi_[sl]-Ai*br_[sl]; } \
  { const int sl=((uu)+2)&7; cr2 += Ar*br_[sl]+Ai*bi_[sl]; ci2 += Ar*bi_[sl]-Ai*br_[sl]; } \
  { const int sl=((uu)+3)&7; cr3 += Ar*br_[sl]+Ai*bi_[sl]; ci3 += Ar*bi_[sl]-Ai*br_[sl]; } \
  { const int sl=((uu)+4)&7; cr4 += Ar*br_[sl]+Ai*bi_[sl]; ci4 += Ar*bi_[sl]-Ai*br_[sl]; } \
  { const int sl=((uu)+5)&7; cr5 += Ar*br_[sl]+Ai*bi_[sl]; ci5 += Ar*bi_[sl]-Ai*br_[sl]; } \
  { const int sl=((uu)+6)&7; cr6 += Ar*br_[sl]+Ai*bi_[sl]; ci6 += Ar*bi_[sl]-Ai*br_[sl]; } \
  { const int sl=((uu)+7)&7; cr7 += Ar*br_[sl]+Ai*bi_[sl]; ci7 += Ar*bi_[sl]-Ai*br_[sl]; } \
} while(0)

// conv step: W(e) = sum A*B (plain product), slot = (k - u) mod 8
#define STEP8C(uu) do { \
  float Ar = ar_[(uu)&7], Ai = ai_[(uu)&7]; \
  { const int sl=(8-(uu))&7;  cr0 += Ar*br_[sl]-Ai*bi_[sl]; ci0 += Ar*bi_[sl]+Ai*br_[sl]; } \
  { const int sl=(9-(uu))&7;  cr1 += Ar*br_[sl]-Ai*bi_[sl]; ci1 += Ar*bi_[sl]+Ai*br_[sl]; } \
  { const int sl=(10-(uu))&7; cr2 += Ar*br_[sl]-Ai*bi_[sl]; ci2 += Ar*bi_[sl]+Ai*br_[sl]; } \
  { const int sl=(11-(uu))&7; cr3 += Ar*br_[sl]-Ai*bi_[sl]; ci3 += Ar*bi_[sl]+Ai*br_[sl]; } \
  { const int sl=(12-(uu))&7; cr4 += Ar*br_[sl]-Ai*bi_[sl]; ci4 += Ar*bi_[sl]+Ai*br_[sl]; } \
  { const int sl=(13-(uu))&7; cr5 += Ar*br_[sl]-Ai*bi_[sl]; ci5 += Ar*bi_[sl]+Ai*br_[sl]; } \
  { const int sl=(14-(uu))&7; cr6 += Ar*br_[sl]-Ai*bi_[sl]; ci6 += Ar*bi_[sl]+Ai*br_[sl]; } \
  { const int sl=(15-(uu))&7; cr7 += Ar*br_[sl]-Ai*bi_[sl]; ci7 += Ar*bi_[sl]+Ai*br_[sl]; } \
} while(0)

// corr tile: lags d0..d0+7; B rows ascend. Cr -> LDS, Ci -> g_C plane0.
#define TILE8(D0) do { \
  const int d0 = (D0); \
  const int x_lo = max(0, -(d0+7)); \
  const int x_hi = min(H, H - d0); \
  const int ng = (x_hi - x_lo + 7) >> 3; \
  float cr0=0,cr1=0,cr2=0,cr3=0,cr4=0,cr5=0,cr6=0,cr7=0; \
  float ci0=0,ci1=0,ci2=0,ci3=0,ci4=0,ci5=0,ci6=0,ci7=0; \
  _Pragma("unroll 1") \
  for (int c = 0; c < 2; ++c) { \
    const float* Ap = g_Arec + ((b*2+c)*AX + x_lo)*102 + 2*om; \
    const float* Bp = sB + c*(BROWS*BST) + (PADB + x_lo + d0)*BST + 2*om; \
    float br_[8], bi_[8], ar_[8], ai_[8]; \
    _Pragma("unroll") \
    for (int s = 0; s < 8; ++s) { \
      float2 bv = *(const float2*)&Bp[s*BST]; \
      br_[s] = bv.x; bi_[s] = bv.y; \
      float2 av = *(const float2*)&Ap[s*102]; \
      ar_[s] = av.x; ai_[s] = av.y; \
    } \
    _Pragma("unroll 1") \
    for (int g = 0; g < ng-1; ++g) { \
      _Pragma("unroll") \
      for (int u = 0; u < 8; ++u) { \
        STEP8(u); \
        float2 bv = *(const float2*)&Bp[(u+8)*BST]; \
        br_[u] = bv.x; bi_[u] = bv.y; \
        float2 av = *(const float2*)&Ap[(u+8)*102]; \
        ar_[u] = av.x; ai_[u] = av.y; \
      } \
      Bp += 8*BST; Ap += 8*102; \
    } \
    _Pragma("unroll") \
    for (int u = 0; u < 8; ++u) { \
      STEP8(u); \
      if (u < 7) { \
        float2 bv = *(const float2*)&Bp[(u+8)*BST]; \
        br_[u] = bv.x; bi_[u] = bv.y; \
      } \
    } \
  } \
  if (omValid) { \
    const float sc = (om == 0 || om == 50) ? 0.5f : 1.0f; \
    const int base = om*CLAG + (d0 + 49); \
    float* crl = CrL + base; \
    float* gci = g_C + (size_t)bid*15300 + base; \
    float4 v0 = {cr0*sc, cr1*sc, cr2*sc, cr3*sc}; \
    float4 w0 = {ci0*sc, ci1*sc, ci2*sc, ci3*sc}; \
    *(float4*)&crl[0] = v0; \
    *(float4*)&gci[0] = w0; \
    if (d0 != 47) { \
      float4 v1 = {cr4*sc, cr5*sc, cr6*sc, cr7*sc}; \
      float4 w1 = {ci4*sc, ci5*sc, ci6*sc, ci7*sc}; \
      *(float4*)&crl[4] = v1; \
      *(float4*)&gci[4] = w1; \
    } \
  } \
} while(0)

// conv tile: W(e0..e0+7); B rows descend. Wr,Wi -> g_C planes 1,2.
#define TILE8C(E0) do { \
  const int e0 = (E0); \
  const int x_lo = max(0, e0 - 49); \
  const int x_hi = min(H, e0 + 8); \
  const int ng = (x_hi - x_lo + 7) >> 3; \
  float cr0=0,cr1=0,cr2=0,cr3=0,cr4=0,cr5=0,cr6=0,cr7=0; \
  float ci0=0,ci1=0,ci2=0,ci3=0,ci4=0,ci5=0,ci6=0,ci7=0; \
  _Pragma("unroll 1") \
  for (int c = 0; c < 2; ++c) { \
    const float* Ap = g_Arec + ((b*2+c)*AX + x_lo)*102 + 2*om; \
    const float* Bq = sB + c*(BROWS*BST) + (PADB + e0 - x_lo)*BST + 2*om; \
    float br_[8], bi_[8], ar_[8], ai_[8]; \
    _Pragma("unroll") \
    for (int s = 0; s < 8; ++s) { \
      float2 bv = *(const float2*)&Bq[s*BST]; \
      br_[s] = bv.x; bi_[s] = bv.y; \
      float2 av = *(const float2*)&Ap[s*102]; \
      ar_[s] = av.x; ai_[s] = av.y; \
    } \
    _Pragma("unroll 1") \
    for (int g = 0; g < ng-1; ++g) { \
      _Pragma("unroll") \
      for (int u = 0; u < 8; ++u) { \
        STEP8C(u); \
        float2 bv = *(const float2*)&Bq[-(u+1)*BST]; \
        br_[7-u] = bv.x; bi_[7-u] = bv.y; \
        float2 av = *(const float2*)&Ap[(u+8)*102]; \
        ar_[u] = av.x; ai_[u] = av.y; \
      } \
      Bq -= 8*BST; Ap += 8*102; \
    } \
    { \
      const int lowcap = -(PADB + e0 - x_lo - 8*(ng-1)); \
      _Pragma("unroll") \
      for (int u = 0; u < 8; ++u) { \
        STEP8C(u); \
        if (u < 7) { \
          int off = -(u+1); if (off < lowcap) off = lowcap; \
          float2 bv = *(const float2*)&Bq[off*BST]; \
          br_[7-u] = bv.x; bi_[7-u] = bv.y; \
        } \
      } \
    } \
  } \
  if (omValid) { \
    const float sc = (om == 0 || om == 50) ? 0.5f : 1.0f; \
    const int base = om*CLAG + e0; \
    float* gwr = g_C + (size_t)bid*15300 + 5100 + base; \
    float* gwi = gwr + 5100; \
    float4 v0 = {cr0*sc, cr1*sc, cr2*sc, cr3*sc}; \
    float4 w0 = {ci0*sc, ci1*sc, ci2*sc, ci3*sc}; \
    *(float4*)&gwr[0] = v0; \
    *(float4*)&gwi[0] = w0; \
    if (e0 != 96) { \
      float4 v1 = {cr4*sc, cr5*sc, cr6*sc, cr7*sc}; \
      float4 w1 = {ci4*sc, ci5*sc, ci6*sc, ci7*sc}; \
      *(float4*)&gwr[4] = v1; \
      *(float4*)&gwi[4] = w1; \
    } \
  } \
} while(0)

#define WAVE_REDUCE_ATOMIC(ANG) do { \
  _Pragma("unroll") \
  for (int off = 32; off > 0; off >>= 1) { \
    float v2 = __shfl_xor(bestV, off, 64); \
    int   p2 = __shfl_xor(bestP, off, 64); \
    if (v2 < bestV || (v2 == bestV && p2 < bestP)) { bestV = v2; bestP = p2; } \
  } \
  if (lane == 0) { \
    unsigned int u = __float_as_uint(bestV); \
    u = (u & 0x80000000u) ? ~u : (u | 0x80000000u); \
    unsigned long long key = ((unsigned long long)u << 21) | \
                             ((unsigned long long)(unsigned)(ANG) << 14) | \
                             (unsigned long long)(unsigned)bestP; \
    atomicMin(&g_key[b], key); \
  } \
} while(0)

// ================= main: per (angle-pair, batch) block, 512 threads =================
__global__ __launch_bounds__(512, 4) void k_main() {
  const int bid = blockIdx.x;
  const int a1 = bid % NANGH;          // pairs with a2 = a1 + 60
  const int b = bid / NANGH;
  const int tid = threadIdx.x;

  // LDS (words):
  //   [0..14076)       sB [2][69][102]        (dead after P3)
  //   [14076..19276)   Rt0/Rt1 (dead after P2); CrL [51][100] during/after P3
  __shared__ __align__(16) float sMem[19276];
  float* sB  = sMem;
  float* Rt0 = sMem + 14076;
  float* Rt1 = sMem + 16676;
  float* CrL = sMem + 14076;

  // P0: zero pad rows of sB (stored rows 0..6 and 57..68, both channels)
  for (int u = tid; u < 2*19*BST; u += 512) {
    int ch = u / (19*BST);
    int r  = (u % (19*BST)) / BST;
    int col = u % BST;
    int row = (r < PADB) ? r : r + 50;
    sB[ch*(BROWS*BST) + row*BST + col] = 0.f;
  }

  // P1: bilinear rotation (angle a1) -> Rt0/Rt1, branchless batched taps
  float angf = 0.05235987755982988f * (float)a1;
  float ca = cosf(angf), sa = sinf(angf);
  const float* L0 = g_ligc + (b*2+0)*H*H;
  const float* L1 = g_ligc + (b*2+1)*H*H;
  for (int p = tid; p < H*H; p += 512) {
    int i = p / H, j = p - (p/H)*H;
    float gy = -1.f + (float)i*(2.f/49.f);
    float gx = -1.f + (float)j*(2.f/49.f);
    float x_in = ca*gx - sa*gy;
    float y_in = sa*gx + ca*gy;
    float px = (x_in + 1.f)*0.5f*49.f;
    float py = (y_in + 1.f)*0.5f*49.f;
    float fx = floorf(px), fy = floorf(py);
    int x0 = (int)fx, y0 = (int)fy;
    int x1 = x0 + 1, y1 = y0 + 1;
    float wx1 = px - fx, wx0 = 1.f - wx1;
    float wy1 = py - fy, wy0 = 1.f - wy1;
    float mx0 = ((unsigned)x0 < (unsigned)H) ? 1.f : 0.f;
    float mx1 = ((unsigned)x1 < (unsigned)H) ? 1.f : 0.f;
    float my0 = ((unsigned)y0 < (unsigned)H) ? 1.f : 0.f;
    float my1 = ((unsigned)y1 < (unsigned)H) ? 1.f : 0.f;
    int x0c = min(max(x0, 0), H-1), x1c = min(max(x1, 0), H-1);
    int y0c = min(max(y0, 0), H-1), y1c = min(max(y1, 0), H-1);
    int o00 = y0c*H + x0c, o01 = y0c*H + x1c;
    int o10 = y1c*H + x0c, o11 = y1c*H + x1c;
    float a00 = L0[o00], a01 = L0[o01], a10 = L0[o10], a11 = L0[o11];
    float b00 = L1[o00], b01 = L1[o01], b10 = L1[o10], b11 = L1[o11];
    float w00 = (wy0*wx0)*(my0*mx0);
    float w01 = (wy0*wx1)*(my0*mx1);
    float w10 = (wy1*wx0)*(my1*mx0);
    float w11 = (wy1*wx1)*(my1*mx1);
    float v0 = 0.f, v1 = 0.f;
    v0 += w00*a00; v1 += w00*b00;
    v0 += w01*a01; v1 += w01*b01;
    v0 += w10*a10; v1 += w10*b10;
    v0 += w11*a11; v1 += w11*b11;
    Rt0[j*RTST + i] = v0;
    Rt1[j*RTST + i] = v1;
  }
  __syncthreads();

  // P2: y-DFT of rotated rows -> sB, both channels (442 units), W reg-prefetched
  if (tid < 442) {
    int c = tid / 221;
    int r = tid % 221;
    int cg = r % 17;
    int it = r / 17;
    int i0 = it*4;
    int col0 = 6*cg;
    float pacc[4][6];
    #pragma unroll
    for (int p = 0; p < 4; ++p)
      #pragma unroll
      for (int q = 0; q < 6; ++q) pacc[p][q] = 0.f;
    const float* rtc = Rt0 + c*(H*RTST) + i0;
    const float* wt = g_W + col0;
    float wc[5][6];
    #pragma unroll
    for (int yy = 0; yy < 5; ++yy)
      #pragma unroll
      for (int q = 0; q < 3; ++q) {
        float2 w2 = *(const float2*)&wt[yy*WST + 2*q];
        wc[yy][2*q] = w2.x; wc[yy][2*q+1] = w2.y;
      }
    #pragma unroll 1
    for (int yc = 0; yc < 50; yc += 5) {
      float wn[5][6];
      const int yb = (yc + 5 < 50) ? (yc + 5) : 0;
      #pragma unroll
      for (int yy = 0; yy < 5; ++yy)
        #pragma unroll
        for (int q = 0; q < 3; ++q) {
          float2 w2 = *(const float2*)&wt[(yb+yy)*WST + 2*q];
          wn[yy][2*q] = w2.x; wn[yy][2*q+1] = w2.y;
        }
      #pragma unroll
      for (int yy = 0; yy < 5; ++yy) {
        float4 rv = *(const float4*)&rtc[(yc+yy)*RTST];
        float rr[4] = {rv.x, rv.y, rv.z, rv.w};
        #pragma unroll
        for (int p = 0; p < 4; ++p)
          #pragma unroll
          for (int q = 0; q < 6; ++q) pacc[p][q] += rr[p]*wc[yy][q];
      }
      #pragma unroll
      for (int yy = 0; yy < 5; ++yy)
        #pragma unroll
        for (int q = 0; q < 6; ++q) wc[yy][q] = wn[yy][q];
    }
    float* dst = sB + c*(BROWS*BST) + col0;
    #pragma unroll
    for (int p = 0; p < 4; ++p) {
      int i = i0 + p;
      if (i < H) {
        #pragma unroll
        for (int q = 0; q < 3; ++q) {
          float2 o = {pacc[p][2*q], pacc[p][2*q+1]};
          *(float2*)&dst[(PADB+i)*BST + 2*q] = o;
        }
      }
    }
  }
  __syncthreads();

  const int wid = tid >> 6, lane = tid & 63;
  const int om = (lane <= 50) ? lane : 50;
  const bool omValid = (lane <= 50);

  // P3: corr tiles (angle a1) + conv tiles (angle a1+60) per schedule
  #pragma unroll 1
  for (int slot = 0; slot < 4; ++slot) {
    const int v = g_sched2[wid][slot];
    if (v == 999) break;
    if (v < 100) { TILE8(v); }
    else         { TILE8C(v - 200); }
  }
  __syncthreads();   // sB reads done; CrL + g_C writes visible block-wide

  // P4 pass 1 (angle a1): Cr from LDS, Ci + twiddles direct from L2
  {
    float bestV = 3.0e38f; int bestP = 0;
    if (tid < 425) {
      int lt = tid % 25;
      int dt = tid / 25;
      int l0 = 4*lt, dy0 = 3*dt;
      float su[4][3], sv[4][3];
      #pragma unroll
      for (int k = 0; k < 4; ++k)
        #pragma unroll
        for (int j = 0; j < 3; ++j) { su[k][j] = 0.f; sv[k][j] = 0.f; }
      const float* crp = CrL + l0;
      const float* cip = g_C + (size_t)bid*15300 + l0;
      const float* tp = g_P + 2*dy0;
      #pragma unroll 3
      for (int om2 = 0; om2 < NBIN; ++om2) {
        float4 c4 = *(const float4*)&crp[om2*CLAG];
        float4 i4 = *(const float4*)&cip[om2*CLAG];
        float2 t0 = *(const float2*)&tp[om2*128];
        float2 t1 = *(const float2*)&tp[om2*128 + 2];
        float2 t2 = *(const float2*)&tp[om2*128 + 4];
        float cc[4] = {c4.x, c4.y, c4.z, c4.w};
        float ii[4] = {i4.x, i4.y, i4.z, i4.w};
        float co[3] = {t0.x, t1.x, t2.x};
        float si[3] = {t0.y, t1.y, t2.y};
        #pragma unroll
        for (int k = 0; k < 4; ++k)
          #pragma unroll
          for (int j = 0; j < 3; ++j) {
            su[k][j] += cc[k]*co[j];
            sv[k][j] += ii[k]*si[j];
          }
      }
      #pragma unroll
      for (int k = 0; k < 4; ++k) {
        int lagIdx = l0 + k;
        if (lagIdx <= 98) {
          int row = lagIdx + 1;
          #pragma unroll
          for (int j = 0; j < 3; ++j) {
            int dy = dy0 + j;
            if (dy <= 49) {
              float vp = su[k][j] - sv[k][j];
              float vm = su[k][j] + sv[k][j];
              int posp = row*SD + (50 + dy);
              int posm = row*SD + (50 - dy);
              if (vp < bestV || (vp == bestV && posp < bestP)) { bestV = vp; bestP = posp; }
              if (vm < bestV || (vm == bestV && posm < bestP)) { bestV = vm; bestP = posm; }
            }
          }
        }
      }
    }
    WAVE_REDUCE_ATOMIC(a1);
  }

  // P4 pass 2 (angle a1+60): Wr, Wi direct from L2; no barrier needed
  {
    float bestV = 3.0e38f; int bestP = 0;
    if (tid < 425) {
      int lt = tid % 25;
      int dt = tid / 25;
      int l0 = 4*lt, dy0 = 3*dt;
      float su[4][3], sv[4][3];
      #pragma unroll
      for (int k = 0; k < 4; ++k)
        #pragma unroll
        for (int j = 0; j < 3; ++j) { su[k][j] = 0.f; sv[k][j] = 0.f; }
      const float* crp = g_C + (size_t)bid*15300 + 5100 + l0;
      const float* cip = g_C + (size_t)bid*15300 + 10200 + l0;
      const float* tp = g_P + 2*dy0;
      #pragma unroll 3
      for (int om2 = 0; om2 < NBIN; ++om2) {
        float4 c4 = *(const float4*)&crp[om2*CLAG];
        float4 i4 = *(const float4*)&cip[om2*CLAG];
        float2 t0 = *(const float2*)&tp[om2*128];
        float2 t1 = *(const float2*)&tp[om2*128 + 2];
        float2 t2 = *(const float2*)&tp[om2*128 + 4];
        float cc[4] = {c4.x, c4.y, c4.z, c4.w};
        float ii[4] = {i4.x, i4.y, i4.z, i4.w};
        float co[3] = {t0.x, t1.x, t2.x};
        float si[3] = {t0.y, t1.y, t2.y};
        #pragma unroll
        for (int k = 0; k < 4; ++k)
          #pragma unroll
          for (int j = 0; j < 3; ++j) {
            su[k][j] += cc[k]*co[j];
            sv[k][j] += ii[k]*si[j];
          }
      }
      #pragma unroll
      for (int k = 0; k < 4; ++k) {
        int e = l0 + k;
        if (e <= 98) {
          int row2 = 99 - e;
          #pragma unroll
          for (int j = 0; j < 3; ++j) {
            int dy = dy0 + j;
            if (dy <= 50) {
              float vp = su[k][j] - sv[k][j];   // S_W at dy' = +dy -> col2 = 99-dy
              int posp = row2*SD + (99 - dy);
              if (vp < bestV || (vp == bestV && posp < bestP)) { bestV = vp; bestP = posp; }
              if (dy >= 2) {
                float vm = su[k][j] + sv[k][j]; // S_W at dy' = 100-dy -> col2 = dy-1
                int posm = row2*SD + (dy - 1);
                if (vm < bestV || (vm == bestV && posm < bestP)) { bestV = vm; bestP = posm; }
              }
            }
          }
        }
      }
    }
    WAVE_REDUCE_ATOMIC(a1 + 60);
  }
}

// ================= final: decode keys, emit outputs =================
__global__ void k_final(float* __restrict__ out) {
  int b = threadIdx.x;
  if (b >= NB) return;
  unsigned long long key = g_key[b];
  int a   = (int)((key >> 14) & 127ULL);
  int pos = (int)(key & 16383ULL);
  out[b] = 0.05235987755982988f * (float)a;
  out[NB + 2*b]     = (float)(pos / SD) - 50.f;
  out[NB + 2*b + 1] = (float)(pos % SD) - 50.f;
}

extern "C" void kernel_launch(void* const* d_in, const int* in_sizes, int n_in,
                              void* d_out, int out_size, void* d_ws, size_t ws_size,
                              hipStream_t stream) {
  const float* rec = (const float*)d_in[0];
  const float* lig = (const float*)d_in[1];
  const float* wr  = (const float*)d_in[2];
  const float* br  = (const float*)d_in[3];
  const float* wsc = (const float*)d_in[4];
  (void)in_sizes; (void)n_in; (void)out_size; (void)d_ws; (void)ws_size;
  hipLaunchKernelGGL(k_prep, dim3(NB*8+1), dim3(512), 0, stream, rec, lig, wr, br, wsc);
  hipLaunchKernelGGL(k_main, dim3(NANGH*NB), dim3(512), 0, stream);
  hipLaunchKernelGGL(k_final, dim3(1), dim3(64), 0, stream, (float*)d_out);
}

// Round 18
// 270.317 us; speedup vs baseline: 1.0840x; 1.0840x over previous
//
#include <hip/hip_runtime.h>
#include <math.h>

#define NANG 120
#define NANGH 60
#define NB   16
#define H    50
#define SD   100
#define NBIN 51        // rfft bins of length-100
#define PADB 7         // top pad rows of B-hat (rows -7..-1 zero)
#define BROWS 69       // stored rows: r in [-7, 61]
#define BST  102       // B-hat row stride
#define WST  104       // g_W row stride
#define RTST 52        // Rt row stride
#define CLAG 100       // C lag dim
#define TST2 104       // sP row stride (dy 0..50 -> 102 words, pad 104)
#define AX   58        // g_Arec x rows (50 real + 8 zero pad)

// ---- device-global scratch ----
__device__ __align__(16) float g_Arec[NB*2*AX*NBIN*2 + 64]; // [b][c][x][om][2], x 50..57 zero
__device__ __align__(16) float g_ligc[NB*2*H*H];            // [b][c][y][x]
__device__ __align__(16) float g_W[H*WST];                  // [y][2*om+p] = (cos, -sin)
__device__ __align__(16) float g_P[NBIN*128 + 64];          // [om][2*dy+p] = (cos,sin), dy 0..50
__device__ __align__(16) float g_C[(size_t)NANGH*NB*15300]; // [pair]{Ci1, Wr, Wi}[51][100]
__device__ unsigned long long g_key[NB];

// per-wave tile schedule (4 slots): corr d0 in [-49,47]; conv encoded e0+200; 999 = none.
// group counts per wave: {13,13,12,12,12,12,12,12}
__device__ const int g_sched2[8][4] = {
  {-1,-17,-49,999},{248,232,200,999},{-9,15,296,999},{240,264,47,999},
  {7,-25,208,999},{256,224,-41,999},{23,-33,216,39},{272,280,31,288}
};

// ================= prep: conv+relu+combine, rec spectrum, tables =================
__global__ __launch_bounds__(512) void k_prep(const float* __restrict__ rec,
                                              const float* __restrict__ lig,
                                              const float* __restrict__ wr,
                                              const float* __restrict__ br,
                                              const float* __restrict__ wsc) {
  const int blk = blockIdx.x;
  const int tid = threadIdx.x;
  if (blk == NB*4) {
    for (int u = tid; u < H*WST; u += 512) {
      int y = u / WST, col = u % WST;
      float v = 0.f;
      if (col < 2*NBIN) {
        int om = col >> 1;
        int k = (om * y) % SD;
        double ang = 6.283185307179586 * (double)k / 100.0;
        v = (col & 1) ? (float)(-sin(ang)) : (float)cos(ang);
      }
      g_W[u] = v;
    }
    for (int u = tid; u < NBIN*128; u += 512) {
      int om = u >> 7, q = u & 127;
      int dy = q >> 1;
      float v = 0.f;
      if (dy <= 50) {
        int k = (om * dy) % SD;
        double ang = 6.283185307179586 * (double)k / 100.0;
        v = (q & 1) ? (float)sin(ang) : (float)cos(ang);
      }
      g_P[u] = v;
    }
    for (int i = tid; i < NB; i += 512) g_key[i] = (0x80000000ULL << 21);
    return;
  }
  const int b = blk >> 2;
  const int part = blk & 3;
  const int omBase = part * 13;
  const int nOm = (part == 3) ? 12 : 13;
  __shared__ float recf[2*H*H];
  __shared__ float tbl[SD*2];
  for (int k = tid; k < SD; k += 512) {
    double ang = 6.283185307179586 * (double)k / 100.0;
    tbl[2*k]   = (float)cos(ang);
    tbl[2*k+1] = (float)sin(ang);
  }
  const float* rimg = rec + b*H*H;
  const float* limg = lig + b*H*H;
  for (int p = tid; p < H*H; p += 512) {
    int i = p / H, j = p - (p/H)*H;
    float ar0 = br[0], ar1 = br[1], al0 = br[0], al1 = br[1];
    for (int di = 0; di < 3; ++di) {
      int ii = i + di - 1;
      if (ii < 0 || ii >= H) continue;
      for (int dj = 0; dj < 3; ++dj) {
        int jj = j + dj - 1;
        if (jj < 0 || jj >= H) continue;
        float rv = rimg[ii*H+jj], lv = limg[ii*H+jj];
        float w0 = wr[di*3 + dj], w1 = wr[9 + di*3 + dj];
        ar0 += w0*rv; ar1 += w1*rv; al0 += w0*lv; al1 += w1*lv;
      }
    }
    ar0 = fmaxf(ar0, 0.f); ar1 = fmaxf(ar1, 0.f);
    recf[p] = ar0; recf[H*H + p] = ar1;
    if (part == 0) {
      al0 = fmaxf(al0, 0.f); al1 = fmaxf(al1, 0.f);
      g_ligc[((b*2+0)*H + i)*H + j] = wsc[0]*al0 + wsc[1]*al1;
      g_ligc[((b*2+1)*H + i)*H + j] = wsc[2]*al0 + wsc[3]*al1;
    }
  }
  if (part == 0) {
    for (int u = tid; u < 2*8*102; u += 512) {
      int c = u / 816; int r = u % 816;
      int x = 50 + r / 102; int q = r % 102;
      g_Arec[((b*2+c)*AX + x)*102 + q] = 0.f;
    }
  }
  __syncthreads();
  for (int u = tid; u < 2*H*nOm; u += 512) {
    int om = omBase + u % nOm;
    int rest = u / nOm; int x = rest % H; int c = rest / H;
    const float* row = recf + (c*H + x)*H;
    float sr = 0.f, si = 0.f;
    int k = 0;
    for (int y = 0; y < H; ++y) {
      float rv = row[y];
      sr += rv * tbl[2*k];
      si -= rv * tbl[2*k+1];
      k += om; if (k >= SD) k -= SD;
    }
    float* dst = g_Arec + ((b*2+c)*AX + x)*102 + 2*om;
    dst[0] = sr; dst[1] = si;
  }
}

// corr step: C(d) = sum conj(A)*B
#define STEP8(uu) do { \
  float Ar = ar_[(uu)&7], Ai = ai_[(uu)&7]; \
  { const int sl=(uu)&7;     cr0 += Ar*br_[sl]+Ai*bi_[sl]; ci0 += Ar*bi_[sl]-Ai*br_[sl]; } \
  { const int sl=((uu)+1)&7; cr1 += Ar*br_[sl]+Ai*bi_[sl]; ci1 += Ar*bi_[sl]-Ai*br_[sl]; } \
  { const int sl=((uu)+2)&7; cr2 += Ar*br_[sl]+Ai*bi_[sl]; ci2 += Ar*bi_[sl]-Ai*br_[sl]; } \
  { const int sl=((uu)+3)&7; cr3 += Ar*br_[sl]+Ai*bi_[sl]; ci3 += Ar*bi_[sl]-Ai*br_[sl]; } \
  { const int sl=((uu)+4)&7; cr4 += Ar*br_[sl]+Ai*bi_[sl]; ci4 += Ar*bi_[sl]-Ai*br_[sl]; } \
  { const int sl=((uu)+5)&7; cr5 += Ar*br_[sl]+Ai*bi_[sl]; ci5 += Ar*bi_[sl]-Ai*br_[sl]; } \
  { const int sl=((uu)+6)&7; cr6 += Ar*br_[sl]+Ai*bi_[sl]; ci6 += Ar*bi_[sl]-Ai*br_[sl]; } \
  { const int sl=((uu)+7)&7; cr7 += Ar*br_[sl]+Ai*bi_[sl]; ci7 += Ar*bi_[sl]-Ai*br_[sl]; } \
} while(0)

// conv step: W(e) = sum A*B (plain product), slot = (k - u) mod 8
#define STEP8C(uu) do { \
  float Ar = ar_[(uu)&7], Ai = ai_[(uu)&7]; \
  { const int sl=(8-(uu))&7;  cr0 += Ar*br_[sl]-Ai*bi_[sl]; ci0 += Ar*bi_[sl]+Ai*br_[sl]; } \
  { const int sl=(9-(uu))&7;  cr1 += Ar*br_[sl]-Ai*bi_[sl]; ci1 += Ar*bi_[sl]+Ai*br_[sl]; } \
  { const int sl=(10-(uu))&7; cr2 += Ar*br_[sl]-Ai*bi_[sl]; ci2 += Ar*bi_[sl]+Ai*br_[sl]; } \
  { const int sl=(11-(uu))&7; cr3 += Ar*br_[sl]-Ai*bi_[sl]; ci3 += Ar*bi_[sl]+Ai*br_[sl]; } \
  { const int sl=(12-(uu))&7; cr4 += Ar*br_[sl]-Ai*bi_[sl]; ci4 += Ar*bi_[sl]+Ai*br_[sl]; } \
  { const int sl=(13-(uu))&7; cr5 += Ar*br_[sl]-Ai*bi_[sl]; ci5 += Ar*bi_[sl]+Ai*br_[sl]; } \
  { const int sl=(14-(uu))&7; cr6 += Ar*br_[sl]-Ai*bi_[sl]; ci6 += Ar*bi_[sl]+Ai*br_[sl]; } \
  { const int sl=(15-(uu))&7; cr7 += Ar*br_[sl]-Ai*bi_[sl]; ci7 += Ar*bi_[sl]+Ai*br_[sl]; } \
} while(0)

// corr tile: lags d0..d0+7; B rows ascend. Cr -> LDS, Ci -> g_C plane0.
#define TILE8(D0) do { \
  const int d0 = (D0); \
  const int x_lo = max(0, -(d0+7)); \
  const int x_hi = min(H, H - d0); \
  const int ng = (x_hi - x_lo + 7) >> 3; \
  float cr0=0,cr1=0,cr2=0,cr3=0,cr4=0,cr5=0,cr6=0,cr7=0; \
  float ci0=0,ci1=0,ci2=0,ci3=0,ci4=0,ci5=0,ci6=0,ci7=0; \
  _Pragma("unroll 1") \
  for (int c = 0; c < 2; ++c) { \
    const float* Ap = g_Arec + ((b*2+c)*AX + x_lo)*102 + 2*om; \
    const float* Bp = sB + c*(BROWS*BST) + (PADB + x_lo + d0)*BST + 2*om; \
    float br_[8], bi_[8], ar_[8], ai_[8]; \
    _Pragma("unroll") \
    for (int s = 0; s < 8; ++s) { \
      float2 bv = *(const float2*)&Bp[s*BST]; \
      br_[s] = bv.x; bi_[s] = bv.y; \
      float2 av = *(const float2*)&Ap[s*102]; \
      ar_[s] = av.x; ai_[s] = av.y; \
    } \
    _Pragma("unroll 1") \
    for (int g = 0; g < ng-1; ++g) { \
      _Pragma("unroll") \
      for (int u = 0; u < 8; ++u) { \
        STEP8(u); \
        float2 bv = *(const float2*)&Bp[(u+8)*BST]; \
        br_[u] = bv.x; bi_[u] = bv.y; \
        float2 av = *(const float2*)&Ap[(u+8)*102]; \
        ar_[u] = av.x; ai_[u] = av.y; \
      } \
      Bp += 8*BST; Ap += 8*102; \
    } \
    _Pragma("unroll") \
    for (int u = 0; u < 8; ++u) { \
      STEP8(u); \
      if (u < 7) { \
        float2 bv = *(const float2*)&Bp[(u+8)*BST]; \
        br_[u] = bv.x; bi_[u] = bv.y; \
      } \
    } \
  } \
  if (omValid) { \
    const float sc = (om == 0 || om == 50) ? 0.5f : 1.0f; \
    const int base = om*CLAG + (d0 + 49); \
    float* crl = CrL + base; \
    float* gci = g_C + (size_t)bid*15300 + base; \
    float4 v0 = {cr0*sc, cr1*sc, cr2*sc, cr3*sc}; \
    float4 w0 = {ci0*sc, ci1*sc, ci2*sc, ci3*sc}; \
    *(float4*)&crl[0] = v0; \
    *(float4*)&gci[0] = w0; \
    if (d0 != 47) { \
      float4 v1 = {cr4*sc, cr5*sc, cr6*sc, cr7*sc}; \
      float4 w1 = {ci4*sc, ci5*sc, ci6*sc, ci7*sc}; \
      *(float4*)&crl[4] = v1; \
      *(float4*)&gci[4] = w1; \
    } \
  } \
} while(0)

// conv tile: W(e0..e0+7); B rows descend. Wr,Wi -> g_C planes 1,2.
#define TILE8C(E0) do { \
  const int e0 = (E0); \
  const int x_lo = max(0, e0 - 49); \
  const int x_hi = min(H, e0 + 8); \
  const int ng = (x_hi - x_lo + 7) >> 3; \
  float cr0=0,cr1=0,cr2=0,cr3=0,cr4=0,cr5=0,cr6=0,cr7=0; \
  float ci0=0,ci1=0,ci2=0,ci3=0,ci4=0,ci5=0,ci6=0,ci7=0; \
  _Pragma("unroll 1") \
  for (int c = 0; c < 2; ++c) { \
    const float* Ap = g_Arec + ((b*2+c)*AX + x_lo)*102 + 2*om; \
    const float* Bq = sB + c*(BROWS*BST) + (PADB + e0 - x_lo)*BST + 2*om; \
    float br_[8], bi_[8], ar_[8], ai_[8]; \
    _Pragma("unroll") \
    for (int s = 0; s < 8; ++s) { \
      float2 bv = *(const float2*)&Bq[s*BST]; \
      br_[s] = bv.x; bi_[s] = bv.y; \
      float2 av = *(const float2*)&Ap[s*102]; \
      ar_[s] = av.x; ai_[s] = av.y; \
    } \
    _Pragma("unroll 1") \
    for (int g = 0; g < ng-1; ++g) { \
      _Pragma("unroll") \
      for (int u = 0; u < 8; ++u) { \
        STEP8C(u); \
        float2 bv = *(const float2*)&Bq[-(u+1)*BST]; \
        br_[7-u] = bv.x; bi_[7-u] = bv.y; \
        float2 av = *(const float2*)&Ap[(u+8)*102]; \
        ar_[u] = av.x; ai_[u] = av.y; \
      } \
      Bq -= 8*BST; Ap += 8*102; \
    } \
    { \
      const int lowcap = -(PADB + e0 - x_lo - 8*(ng-1)); \
      _Pragma("unroll") \
      for (int u = 0; u < 8; ++u) { \
        STEP8C(u); \
        if (u < 7) { \
          int off = -(u+1); if (off < lowcap) off = lowcap; \
          float2 bv = *(const float2*)&Bq[off*BST]; \
          br_[7-u] = bv.x; bi_[7-u] = bv.y; \
        } \
      } \
    } \
  } \
  if (omValid) { \
    const float sc = (om == 0 || om == 50) ? 0.5f : 1.0f; \
    const int base = om*CLAG + e0; \
    float* gwr = g_C + (size_t)bid*15300 + 5100 + base; \
    float* gwi = gwr + 5100; \
    float4 v0 = {cr0*sc, cr1*sc, cr2*sc, cr3*sc}; \
    float4 w0 = {ci0*sc, ci1*sc, ci2*sc, ci3*sc}; \
    *(float4*)&gwr[0] = v0; \
    *(float4*)&gwi[0] = w0; \
    if (e0 != 96) { \
      float4 v1 = {cr4*sc, cr5*sc, cr6*sc, cr7*sc}; \
      float4 w1 = {ci4*sc, ci5*sc, ci6*sc, ci7*sc}; \
      *(float4*)&gwr[4] = v1; \
      *(float4*)&gwi[4] = w1; \
    } \
  } \
} while(0)

#define WAVE_REDUCE_ATOMIC(ANG) do { \
  _Pragma("unroll") \
  for (int off = 32; off > 0; off >>= 1) { \
    float v2 = __shfl_xor(bestV, off, 64); \
    int   p2 = __shfl_xor(bestP, off, 64); \
    if (v2 < bestV || (v2 == bestV && p2 < bestP)) { bestV = v2; bestP = p2; } \
  } \
  if (lane == 0) { \
    unsigned int u = __float_as_uint(bestV); \
    u = (u & 0x80000000u) ? ~u : (u | 0x80000000u); \
    unsigned long long key = ((unsigned long long)u << 21) | \
                             ((unsigned long long)(unsigned)(ANG) << 14) | \
                             (unsigned long long)(unsigned)bestP; \
    atomicMin(&g_key[b], key); \
  } \
} while(0)

// ================= main: per (angle-pair, batch) block, 512 threads =================
__global__ __launch_bounds__(512, 4) void k_main() {
  const int bid = blockIdx.x;
  const int a1 = bid % NANGH;          // pairs with a2 = a1 + 60
  const int b = bid / NANGH;
  const int tid = threadIdx.x;

  // LDS (words):
  //   [0..14076)       sB [2][69][102]        (dead after P3)
  //   [14076..19276)   Rt0/Rt1 (dead after P2); CrL [51][100] during/after P3
  //   [5100..10404)    sP [51][104] (written after P3, over dead sB)
  __shared__ __align__(16) float sMem[19276];
  float* sB  = sMem;
  float* Rt0 = sMem + 14076;
  float* Rt1 = sMem + 16676;
  float* CrL = sMem + 14076;
  float* sP  = sMem + 5100;

  // P0: zero pad rows of sB (stored rows 0..6 and 57..68, both channels)
  for (int u = tid; u < 2*19*BST; u += 512) {
    int ch = u / (19*BST);
    int r  = (u % (19*BST)) / BST;
    int col = u % BST;
    int row = (r < PADB) ? r : r + 50;
    sB[ch*(BROWS*BST) + row*BST + col] = 0.f;
  }

  // P1: bilinear rotation (angle a1) -> Rt0/Rt1, branchless batched taps
  float angf = 0.05235987755982988f * (float)a1;
  float ca = cosf(angf), sa = sinf(angf);
  const float* L0 = g_ligc + (b*2+0)*H*H;
  const float* L1 = g_ligc + (b*2+1)*H*H;
  for (int p = tid; p < H*H; p += 512) {
    int i = p / H, j = p - (p/H)*H;
    float gy = -1.f + (float)i*(2.f/49.f);
    float gx = -1.f + (float)j*(2.f/49.f);
    float x_in = ca*gx - sa*gy;
    float y_in = sa*gx + ca*gy;
    float px = (x_in + 1.f)*0.5f*49.f;
    float py = (y_in + 1.f)*0.5f*49.f;
    float fx = floorf(px), fy = floorf(py);
    int x0 = (int)fx, y0 = (int)fy;
    int x1 = x0 + 1, y1 = y0 + 1;
    float wx1 = px - fx, wx0 = 1.f - wx1;
    float wy1 = py - fy, wy0 = 1.f - wy1;
    float mx0 = ((unsigned)x0 < (unsigned)H) ? 1.f : 0.f;
    float mx1 = ((unsigned)x1 < (unsigned)H) ? 1.f : 0.f;
    float my0 = ((unsigned)y0 < (unsigned)H) ? 1.f : 0.f;
    float my1 = ((unsigned)y1 < (unsigned)H) ? 1.f : 0.f;
    int x0c = min(max(x0, 0), H-1), x1c = min(max(x1, 0), H-1);
    int y0c = min(max(y0, 0), H-1), y1c = min(max(y1, 0), H-1);
    int o00 = y0c*H + x0c, o01 = y0c*H + x1c;
    int o10 = y1c*H + x0c, o11 = y1c*H + x1c;
    float a00 = L0[o00], a01 = L0[o01], a10 = L0[o10], a11 = L0[o11];
    float b00 = L1[o00], b01 = L1[o01], b10 = L1[o10], b11 = L1[o11];
    float w00 = (wy0*wx0)*(my0*mx0);
    float w01 = (wy0*wx1)*(my0*mx1);
    float w10 = (wy1*wx0)*(my1*mx0);
    float w11 = (wy1*wx1)*(my1*mx1);
    float v0 = 0.f, v1 = 0.f;
    v0 += w00*a00; v1 += w00*b00;
    v0 += w01*a01; v1 += w01*b01;
    v0 += w10*a10; v1 += w10*b10;
    v0 += w11*a11; v1 += w11*b11;
    Rt0[j*RTST + i] = v0;
    Rt1[j*RTST + i] = v1;
  }
  __syncthreads();

  // P2: y-DFT of rotated rows -> sB, both channels (442 units), W reg-prefetched
  if (tid < 442) {
    int c = tid / 221;
    int r = tid % 221;
    int cg = r % 17;
    int it = r / 17;
    int i0 = it*4;
    int col0 = 6*cg;
    float pacc[4][6];
    #pragma unroll
    for (int p = 0; p < 4; ++p)
      #pragma unroll
      for (int q = 0; q < 6; ++q) pacc[p][q] = 0.f;
    const float* rtc = Rt0 + c*(H*RTST) + i0;
    const float* wt = g_W + col0;
    float wc[5][6];
    #pragma unroll
    for (int yy = 0; yy < 5; ++yy)
      #pragma unroll
      for (int q = 0; q < 3; ++q) {
        float2 w2 = *(const float2*)&wt[yy*WST + 2*q];
        wc[yy][2*q] = w2.x; wc[yy][2*q+1] = w2.y;
      }
    #pragma unroll 1
    for (int yc = 0; yc < 50; yc += 5) {
      float wn[5][6];
      const int yb = (yc + 5 < 50) ? (yc + 5) : 0;
      #pragma unroll
      for (int yy = 0; yy < 5; ++yy)
        #pragma unroll
        for (int q = 0; q < 3; ++q) {
          float2 w2 = *(const float2*)&wt[(yb+yy)*WST + 2*q];
          wn[yy][2*q] = w2.x; wn[yy][2*q+1] = w2.y;
        }
      #pragma unroll
      for (int yy = 0; yy < 5; ++yy) {
        float4 rv = *(const float4*)&rtc[(yc+yy)*RTST];
        float rr[4] = {rv.x, rv.y, rv.z, rv.w};
        #pragma unroll
        for (int p = 0; p < 4; ++p)
          #pragma unroll
          for (int q = 0; q < 6; ++q) pacc[p][q] += rr[p]*wc[yy][q];
      }
      #pragma unroll
      for (int yy = 0; yy < 5; ++yy)
        #pragma unroll
        for (int q = 0; q < 6; ++q) wc[yy][q] = wn[yy][q];
    }
    float* dst = sB + c*(BROWS*BST) + col0;
    #pragma unroll
    for (int p = 0; p < 4; ++p) {
      int i = i0 + p;
      if (i < H) {
        #pragma unroll
        for (int q = 0; q < 3; ++q) {
          float2 o = {pacc[p][2*q], pacc[p][2*q+1]};
          *(float2*)&dst[(PADB+i)*BST + 2*q] = o;
        }
      }
    }
  }
  __syncthreads();

  const int wid = tid >> 6, lane = tid & 63;
  const int om = (lane <= 50) ? lane : 50;
  const bool omValid = (lane <= 50);

  // P3: corr tiles (angle a1) + conv tiles (angle a1+60) per schedule
  #pragma unroll 1
  for (int slot = 0; slot < 4; ++slot) {
    const int v = g_sched2[wid][slot];
    if (v == 999) break;
    if (v < 100) { TILE8(v); }
    else         { TILE8C(v - 200); }
  }
  __syncthreads();   // sB reads done; CrL + g_C writes visible block-wide

  // repack g_P -> sP (dy 0..50, stride 104) over dead sB
  for (int u = tid; u < 51*51; u += 512) {
    int o = u / 51, dy = u % 51;
    *(float2*)&sP[o*TST2 + 2*dy] = *(const float2*)&g_P[o*128 + 2*dy];
  }
  __syncthreads();

  // P4 pass 1 (angle a1): Cr from LDS, Ci direct from L2
  {
    float bestV = 3.0e38f; int bestP = 0;
    if (tid < 425) {
      int lt = tid % 25;
      int dt = tid / 25;
      int l0 = 4*lt, dy0 = 3*dt;
      float su[4][3], sv[4][3];
      #pragma unroll
      for (int k = 0; k < 4; ++k)
        #pragma unroll
        for (int j = 0; j < 3; ++j) { su[k][j] = 0.f; sv[k][j] = 0.f; }
      const float* crp = CrL + l0;
      const float* cip = g_C + (size_t)bid*15300 + l0;
      const float* tp = sP + 2*dy0;
      #pragma unroll 3
      for (int om2 = 0; om2 < NBIN; ++om2) {
        float4 c4 = *(const float4*)&crp[om2*CLAG];
        float4 i4 = *(const float4*)&cip[om2*CLAG];
        float2 t0 = *(const float2*)&tp[om2*TST2];
        float2 t1 = *(const float2*)&tp[om2*TST2 + 2];
        float2 t2 = *(const float2*)&tp[om2*TST2 + 4];
        float cc[4] = {c4.x, c4.y, c4.z, c4.w};
        float ii[4] = {i4.x, i4.y, i4.z, i4.w};
        float co[3] = {t0.x, t1.x, t2.x};
        float si[3] = {t0.y, t1.y, t2.y};
        #pragma unroll
        for (int k = 0; k < 4; ++k)
          #pragma unroll
          for (int j = 0; j < 3; ++j) {
            su[k][j] += cc[k]*co[j];
            sv[k][j] += ii[k]*si[j];
          }
      }
      #pragma unroll
      for (int k = 0; k < 4; ++k) {
        int lagIdx = l0 + k;
        if (lagIdx <= 98) {
          int row = lagIdx + 1;
          #pragma unroll
          for (int j = 0; j < 3; ++j) {
            int dy = dy0 + j;
            if (dy <= 49) {
              float vp = su[k][j] - sv[k][j];
              float vm = su[k][j] + sv[k][j];
              int posp = row*SD + (50 + dy);
              int posm = row*SD + (50 - dy);
              if (vp < bestV || (vp == bestV && posp < bestP)) { bestV = vp; bestP = posp; }
              if (vm < bestV || (vm == bestV && posm < bestP)) { bestV = vm; bestP = posm; }
            }
          }
        }
      }
    }
    WAVE_REDUCE_ATOMIC(a1);
  }

  // P4 pass 2 (angle a1+60): Wr, Wi direct from L2; no barrier needed (no LDS writes)
  {
    float bestV = 3.0e38f; int bestP = 0;
    if (tid < 425) {
      int lt = tid % 25;
      int dt = tid / 25;
      int l0 = 4*lt, dy0 = 3*dt;
      float su[4][3], sv[4][3];
      #pragma unroll
      for (int k = 0; k < 4; ++k)
        #pragma unroll
        for (int j = 0; j < 3; ++j) { su[k][j] = 0.f; sv[k][j] = 0.f; }
      const float* crp = g_C + (size_t)bid*15300 + 5100 + l0;
      const float* cip = g_C + (size_t)bid*15300 + 10200 + l0;
      const float* tp = sP + 2*dy0;
      #pragma unroll 3
      for (int om2 = 0; om2 < NBIN; ++om2) {
        float4 c4 = *(const float4*)&crp[om2*CLAG];
        float4 i4 = *(const float4*)&cip[om2*CLAG];
        float2 t0 = *(const float2*)&tp[om2*TST2];
        float2 t1 = *(const float2*)&tp[om2*TST2 + 2];
        float2 t2 = *(const float2*)&tp[om2*TST2 + 4];
        float cc[4] = {c4.x, c4.y, c4.z, c4.w};
        float ii[4] = {i4.x, i4.y, i4.z, i4.w};
        float co[3] = {t0.x, t1.x, t2.x};
        float si[3] = {t0.y, t1.y, t2.y};
        #pragma unroll
        for (int k = 0; k < 4; ++k)
          #pragma unroll
          for (int j = 0; j < 3; ++j) {
            su[k][j] += cc[k]*co[j];
            sv[k][j] += ii[k]*si[j];
          }
      }
      #pragma unroll
      for (int k = 0; k < 4; ++k) {
        int e = l0 + k;
        if (e <= 98) {
          int row2 = 99 - e;
          #pragma unroll
          for (int j = 0; j < 3; ++j) {
            int dy = dy0 + j;
            if (dy <= 50) {
              float vp = su[k][j] - sv[k][j];   // S_W at dy' = +dy -> col2 = 99-dy
              int posp = row2*SD + (99 - dy);
              if (vp < bestV || (vp == bestV && posp < bestP)) { bestV = vp; bestP = posp; }
              if (dy >= 2) {
                float vm = su[k][j] + sv[k][j]; // S_W at dy' = 100-dy -> col2 = dy-1
                int posm = row2*SD + (dy - 1);
                if (vm < bestV || (vm == bestV && posm < bestP)) { bestV = vm; bestP = posm; }
              }
            }
          }
        }
      }
    }
    WAVE_REDUCE_ATOMIC(a1 + 60);
  }
}

// ================= final: decode keys, emit outputs =================
__global__ void k_final(float* __restrict__ out) {
  int b = threadIdx.x;
  if (b >= NB) return;
  unsigned long long key = g_key[b];
  int a   = (int)((key >> 14) & 127ULL);
  int pos = (int)(key & 16383ULL);
  out[b] = 0.05235987755982988f * (float)a;
  out[NB + 2*b]     = (float)(pos / SD) - 50.f;
  out[NB + 2*b + 1] = (float)(pos % SD) - 50.f;
}

extern "C" void kernel_launch(void* const* d_in, const int* in_sizes, int n_in,
                              void* d_out, int out_size, void* d_ws, size_t ws_size,
                              hipStream_t stream) {
  const float* rec = (const float*)d_in[0];
  const float* lig = (const float*)d_in[1];
  const float* wr  = (const float*)d_in[2];
  const float* br  = (const float*)d_in[3];
  const float* wsc = (const float*)d_in[4];
  (void)in_sizes; (void)n_in; (void)out_size; (void)d_ws; (void)ws_size;
  hipLaunchKernelGGL(k_prep, dim3(NB*4+1), dim3(512), 0, stream, rec, lig, wr, br, wsc);
  hipLaunchKernelGGL(k_main, dim3(NANGH*NB), dim3(512), 0, stream);
  hipLaunchKernelGGL(k_final, dim3(1), dim3(64), 0, stream, (float*)d_out);
}